// Round 5
// baseline (420.283 us; speedup 1.0000x reference)
//
#include <hip/hip_runtime.h>
#include <hip/hip_fp16.h>

// NNUE forward: out = MLP(clip(concat(Wf@w_in^T+b, Bf@w_in^T+b)))
// Big GEMM: M=8192, N=256, K=40960. ~1.38 GB mandatory reads.
// fp16 MFMA 16x16x32, f32 accumulate, f32->f16 cvt fused into LDS staging.
//
// v5 (from r4 post-mortem): __syncthreads() drains vmcnt(0) at every step,
// killing the cross-barrier reg prefetch (m218 mechanism). Replace with
// raw s_barrier + explicit lgkmcnt(0) flush (verified plain-HIP pattern,
// learn_hip m194-m201): global loads stay in flight across barriers,
// consumed via counted vmcnt dependency waits. Everything else unchanged:
// BM=128 BN=256 BK=32, 512 thr (8 waves, 2Mx4N), KS=8 -> 512 blocks, 2/CU,
// conflict-free ((row>>1)&3)<<4 XOR swizzle, double-buffered LDS.

#define FEAT 40960
#define PSTRIDE (8192ull * 256ull)
#define KSPLIT 8
#define KCHUNK (FEAT / KSPLIT)   // 5120
#define NSTEPS (KCHUNK / 32)     // 160

using floatx4 = __attribute__((ext_vector_type(4))) float;
using half8   = __attribute__((ext_vector_type(8))) _Float16;
using half4   = __attribute__((ext_vector_type(4))) _Float16;

// Barrier that does NOT drain vmcnt: flush LDS ops, raw s_barrier.
// (asm "memory" clobber pins the preceding ds_writes before the flush.)
__device__ __forceinline__ void lds_barrier() {
    asm volatile("s_waitcnt lgkmcnt(0)" ::: "memory");
    __builtin_amdgcn_s_barrier();
}

// ---------------------------------------------------------------------------
// GEMM: 512 threads = 8 waves (2M x 4N), wave tile 64x64 (acc 4x4 = 64 regs).
// ---------------------------------------------------------------------------
template <typename PT>
__global__ __launch_bounds__(512, 4) void nnue_gemm8(
    const float* __restrict__ white, const float* __restrict__ black,
    const float* __restrict__ w_in, PT* __restrict__ P)
{
    __shared__ __align__(16) _Float16 As[2][128 * 32];   // 16 KB
    __shared__ __align__(16) _Float16 Ws[2][256 * 32];   // 32 KB

    const int tid  = threadIdx.x;
    const int lane = tid & 63;
    const int wave = tid >> 6;    // 0..7
    const int wm   = wave >> 2;   // 0..1 (M)
    const int wn   = wave & 3;    // 0..3 (N)

    const int mb = blockIdx.x & 63;
    const int ks = blockIdx.x >> 6;

    const float* Abase = (mb < 32)
        ? (white + (size_t)mb * 128 * FEAT)
        : (black + (size_t)(mb - 32) * 128 * FEAT);
    const int k0 = ks * KCHUNK;

    // staging: A tile 128x32 f32 (2 float4/thread), W 256x32 (4 float4/thread)
    const int c4    = tid & 7;               // float4 column (8 per row)
    const int row0  = tid >> 3;              // 0..63
    // conflict-free involution: XOR bits 4..5 of byte offset with (row>>1)&3
    const int swz_w = ((row0 >> 1) & 3) << 4;
    const int woff  = (c4 * 8) ^ swz_w;

    // fragment geometry (mfma_f32_16x16x32_f16):
    // operand: lane reads row (lane&15), k-halves (lane>>4)*8..+7 (16B)
    // C/D:     row = (lane>>4)*4 + reg, col = lane&15
    const int frow  = lane & 15;
    const int fhi   = lane >> 4;
    const int swz_r = ((frow >> 1) & 3) << 4;
    const int kb    = (fhi * 16) ^ swz_r;    // byte offset within 64B row

    floatx4 acc[4][4];
    const floatx4 zero = {0.f, 0.f, 0.f, 0.f};
#pragma unroll
    for (int m = 0; m < 4; ++m)
#pragma unroll
        for (int n = 0; n < 4; ++n) acc[m][n] = zero;

    floatx4 ra[2], rw[4];

    auto issue = [&](int kglob) {
#pragma unroll
        for (int i = 0; i < 2; ++i)
            ra[i] = *reinterpret_cast<const floatx4*>(
                Abase + (size_t)(row0 + 64 * i) * FEAT + kglob + c4 * 4);
#pragma unroll
        for (int i = 0; i < 4; ++i)
            rw[i] = *reinterpret_cast<const floatx4*>(
                w_in + (size_t)(row0 + 64 * i) * FEAT + kglob + c4 * 4);
    };

    auto cvtStore = [&](int buf) {
#pragma unroll
        for (int i = 0; i < 2; ++i) {
            half4 h;
#pragma unroll
            for (int j = 0; j < 4; ++j) h[j] = (_Float16)ra[i][j];   // RNE
            *reinterpret_cast<half4*>(
                reinterpret_cast<char*>(&As[buf][0]) + (row0 + 64 * i) * 64 + woff) = h;
        }
#pragma unroll
        for (int i = 0; i < 4; ++i) {
            half4 h;
#pragma unroll
            for (int j = 0; j < 4; ++j) h[j] = (_Float16)rw[i][j];
            *reinterpret_cast<half4*>(
                reinterpret_cast<char*>(&Ws[buf][0]) + (row0 + 64 * i) * 64 + woff) = h;
        }
    };

    auto mfmaStep = [&](int buf) {
        half8 bf[4];
#pragma unroll
        for (int n = 0; n < 4; ++n) {
            const int r = wn * 64 + n * 16 + frow;
            bf[n] = *reinterpret_cast<const half8*>(
                reinterpret_cast<const char*>(&Ws[buf][0]) + r * 64 + kb);
        }
#pragma unroll
        for (int m = 0; m < 4; ++m) {
            const int r = wm * 64 + m * 16 + frow;
            half8 af = *reinterpret_cast<const half8*>(
                reinterpret_cast<const char*>(&As[buf][0]) + r * 64 + kb);
#pragma unroll
            for (int n = 0; n < 4; ++n)
                acc[m][n] = __builtin_amdgcn_mfma_f32_16x16x32_f16(af, bf[n], acc[m][n], 0, 0, 0);
        }
    };

    // prologue: tile 0 -> buf0, tile 1 in flight
    issue(k0);
    cvtStore(0);
    issue(k0 + 32);
    lds_barrier();

    // steady state, one raw barrier per step; vmcnt NEVER drained in-loop:
    //   mfma(buf t) ; cvtStore(buf t+1) <- loads issued at t-1 (counted vmcnt
    //   dep wait) ; issue(t+2) flies across the barrier.
    for (int t = 0; t < NSTEPS; ++t) {
        mfmaStep(t & 1);
        if (t + 1 < NSTEPS) {
            cvtStore((t + 1) & 1);
            if (t + 2 < NSTEPS) issue(k0 + (t + 2) * 32);
        }
        lds_barrier();
    }

    // epilogue: partial C (pre-bias, pre-clip) to workspace
    PT* Pb = P + (size_t)ks * PSTRIDE + (size_t)mb * 128 * 256;
#pragma unroll
    for (int m = 0; m < 4; ++m)
#pragma unroll
        for (int n = 0; n < 4; ++n)
#pragma unroll
            for (int r = 0; r < 4; ++r) {
                const int row = wm * 64 + m * 16 + fhi * 4 + r;
                const int col = wn * 64 + n * 16 + frow;
                Pb[(size_t)row * 256 + col] = (PT)acc[m][n][r];
            }
}

// ---------------------------------------------------------------------------
// Tail: reduce 8 K-split partials + b_in + clip -> x[.,512], then the 3 tiny
// layers. One block per 32 batch rows.
// ---------------------------------------------------------------------------
template <typename PT>
__global__ __launch_bounds__(256) void nnue_tail8(
    const PT* __restrict__ P,
    const float* __restrict__ b_in,
    const float* __restrict__ w_h1, const float* __restrict__ b_h1,
    const float* __restrict__ w_h2, const float* __restrict__ b_h2,
    const float* __restrict__ w_out, const float* __restrict__ b_out,
    float* __restrict__ out)
{
    __shared__ float xs[32][512];
    __shared__ float w1[32][513];
    __shared__ float w2[32][33];
    __shared__ float h1[32][33];
    __shared__ float h2[32][33];
    __shared__ float wo[32];

    const int tid = threadIdx.x;
    const int b0  = blockIdx.x * 32;

    for (int i = tid; i < 32 * 512; i += 256) w1[i >> 9][i & 511] = w_h1[i];
    for (int i = tid; i < 32 * 32; i += 256)  w2[i >> 5][i & 31]  = w_h2[i];
    if (tid < 32) wo[tid] = w_out[tid];

    for (int i = tid; i < 32 * 512; i += 256) {
        const int r = i >> 9, c = i & 511;
        const int persp = c >> 8, n = c & 255;
        const size_t prow = (size_t)(b0 + r) + (persp ? 4096u : 0u);
        float v = 0.f;
#pragma unroll
        for (int s = 0; s < KSPLIT; ++s)
            v += (float)P[(size_t)s * PSTRIDE + prow * 256 + n];
        v += b_in[n];
        xs[r][c] = fminf(fmaxf(v, 0.f), 1.f);
    }
    __syncthreads();

    for (int p = tid; p < 32 * 32; p += 256) {
        const int o = p & 31, r = p >> 5;
        float a = b_h1[o];
        for (int j = 0; j < 512; ++j) a += xs[r][j] * w1[o][j];
        h1[r][o] = fminf(fmaxf(a, 0.f), 1.f);
    }
    __syncthreads();

    for (int p = tid; p < 32 * 32; p += 256) {
        const int o = p & 31, r = p >> 5;
        float a = b_h2[o];
        for (int j = 0; j < 32; ++j) a += h1[r][j] * w2[o][j];
        h2[r][o] = fminf(fmaxf(a, 0.f), 1.f);
    }
    __syncthreads();

    if (tid < 32) {
        float a = b_out[0];
        for (int j = 0; j < 32; ++j) a += h2[tid][j] * wo[j];
        out[b0 + tid] = a;
    }
}

// ---------------------------------------------------------------------------
// Emergency fallback (ws too small for any split): slow but correct.
// ---------------------------------------------------------------------------
__global__ __launch_bounds__(256) void nnue_naive(
    const float* __restrict__ white, const float* __restrict__ black,
    const float* __restrict__ w_in, const float* __restrict__ b_in,
    const float* __restrict__ w_h1, const float* __restrict__ b_h1,
    const float* __restrict__ w_h2, const float* __restrict__ b_h2,
    const float* __restrict__ w_out, const float* __restrict__ b_out,
    float* __restrict__ out)
{
    __shared__ float feat[4096];
    __shared__ float xs[512];
    __shared__ float h1s[32];
    __shared__ float h2s[32];
    const int b = blockIdx.x, tid = threadIdx.x;
    float acc0 = 0.f, acc1 = 0.f;
    for (int c = 0; c < FEAT; c += 2048) {
        for (int i = tid; i < 2048; i += 256) {
            feat[i]        = white[(size_t)b * FEAT + c + i];
            feat[2048 + i] = black[(size_t)b * FEAT + c + i];
        }
        __syncthreads();
        const float* wr = w_in + (size_t)tid * FEAT + c;
        for (int k = 0; k < 2048; ++k) {
            const float w = wr[k];
            acc0 += feat[k] * w;
            acc1 += feat[2048 + k] * w;
        }
        __syncthreads();
    }
    xs[tid]       = fminf(fmaxf(acc0 + b_in[tid], 0.f), 1.f);
    xs[256 + tid] = fminf(fmaxf(acc1 + b_in[tid], 0.f), 1.f);
    __syncthreads();
    if (tid < 32) {
        float a = b_h1[tid];
        for (int j = 0; j < 512; ++j) a += xs[j] * w_h1[tid * 512 + j];
        h1s[tid] = fminf(fmaxf(a, 0.f), 1.f);
    }
    __syncthreads();
    if (tid < 32) {
        float a = b_h2[tid];
        for (int j = 0; j < 32; ++j) a += h1s[j] * w_h2[tid * 32 + j];
        h2s[tid] = fminf(fmaxf(a, 0.f), 1.f);
    }
    __syncthreads();
    if (tid == 0) {
        float a = b_out[0];
        for (int j = 0; j < 32; ++j) a += h2s[j] * w_out[j];
        out[b] = a;
    }
}

extern "C" void kernel_launch(void* const* d_in, const int* in_sizes, int n_in,
                              void* d_out, int out_size, void* d_ws, size_t ws_size,
                              hipStream_t stream)
{
    const float* white = (const float*)d_in[0];
    const float* black = (const float*)d_in[1];
    const float* w_in  = (const float*)d_in[2];
    const float* b_in  = (const float*)d_in[3];
    const float* w_h1  = (const float*)d_in[4];
    const float* b_h1  = (const float*)d_in[5];
    const float* w_h2  = (const float*)d_in[6];
    const float* b_h2  = (const float*)d_in[7];
    const float* w_out = (const float*)d_in[8];
    const float* b_out = (const float*)d_in[9];
    float* out = (float*)d_out;

    const size_t f32Need = KSPLIT * PSTRIDE * sizeof(float);     // 64 MB
    const size_t f16Need = KSPLIT * PSTRIDE * sizeof(_Float16);  // 32 MB

    if (ws_size >= f32Need) {
        float* P = (float*)d_ws;
        nnue_gemm8<float><<<dim3(64 * KSPLIT), 512, 0, stream>>>(white, black, w_in, P);
        nnue_tail8<float><<<dim3(128), 256, 0, stream>>>(P, b_in, w_h1, b_h1,
                                                         w_h2, b_h2, w_out, b_out, out);
    } else if (ws_size >= f16Need) {
        _Float16* P = (_Float16*)d_ws;
        nnue_gemm8<_Float16><<<dim3(64 * KSPLIT), 512, 0, stream>>>(white, black, w_in, P);
        nnue_tail8<_Float16><<<dim3(128), 256, 0, stream>>>(P, b_in, w_h1, b_h1,
                                                            w_h2, b_h2, w_out, b_out, out);
    } else {
        nnue_naive<<<4096, 256, 0, stream>>>(white, black, w_in, b_in, w_h1, b_h1,
                                             w_h2, b_h2, w_out, b_out, out);
    }
}